// Round 13
// baseline (314.197 us; speedup 1.0000x reference)
//
#include <hip/hip_runtime.h>
#include <math.h>

#define NN 100000
#define NE 1600000
#define BSZ 64                          // dst nodes per bucket
#define NBUCK ((NN + BSZ - 1) / BSZ)    // 1563
#define NBLK 256                        // scatter blocks / hist columns
#define CHUNK ((NE + NBLK - 1) / NBLK)  // 6250 edges per block
#define NH (NBUCK * NBLK)               // 400128 hist entries
#define NSB ((NH + 1023) / 1024)        // 391 scan blocks

typedef unsigned int uint;
typedef unsigned short ushort_t;
typedef float f32x4 __attribute__((ext_vector_type(4)));
typedef short s16x8 __attribute__((ext_vector_type(8)));

union U4S8 { uint4 u; s16x8 s; };

// bf16 helpers (RNE pack, shift-decode)
__device__ inline uint bf16_1(float f) {
  uint u = __float_as_uint(f);
  return (u + 0x7FFFu + ((u >> 16) & 1u)) >> 16;
}
__device__ inline uint bf16_2(float lo, float hi) {
  return bf16_1(lo) | (bf16_1(hi) << 16);
}

__device__ inline f32x4 mfma_bf16(uint4 a, uint4 b, f32x4 c) {
  U4S8 ua, ub; ua.u = a; ub.u = b;
  return __builtin_amdgcn_mfma_f32_16x16x32_bf16(ua.s, ub.s, c, 0, 0, 0);
}

// Accumulate the two bf16 halves of u into alo/ahi via v_dot2_f32_bf16.
// Masks (1.0,0.0)/(0.0,1.0) select exactly; products are exact in f32.
__device__ inline void dot2acc2(float& alo, float& ahi, uint u) {
  asm("v_dot2_f32_bf16 %0, %2, %3, %0\n\t"
      "v_dot2_f32_bf16 %1, %2, %4, %1"
      : "+v"(alo), "+v"(ahi)
      : "v"(u), "v"(0x00003F80u), "v"(0x3F800000u));
}

// ---------------------------------------------------------------------------
// x (fp32 [NN][128]) -> xs SLICE-MAJOR bf16: xs[s][node][8 uints], s=u>>3.
// Slice = 3.2 MB -> fits one XCD's 4 MB L2.
// ---------------------------------------------------------------------------
__global__ __launch_bounds__(256) void tobf16_kernel(
    const float* __restrict__ x, uint* __restrict__ xs) {
  int i = blockIdx.x * 256 + threadIdx.x;
  if (i >= NN * 16) return;
  const float4* p = (const float4*)x + (size_t)i * 2;
  float4 a = p[0], b = p[1];
  uint4 o;
  o.x = bf16_2(a.x, a.y);
  o.y = bf16_2(a.z, a.w);
  o.z = bf16_2(b.x, b.y);
  o.w = bf16_2(b.z, b.w);
  int r = i >> 4;
  int u = (i & 15) * 4;          // uint index 0..60
  *(uint4*)(xs + (size_t)(u >> 3) * NN * 8 + (size_t)r * 8 + (u & 7)) = o;
}

// ---------------------------------------------------------------------------
// Weight prep: w1t[col][k] = bf16([ws1;wn1][k][col]), K=256 -> 128 uints/row.
// ---------------------------------------------------------------------------
__global__ __launch_bounds__(256) void prep_w1_kernel(
    const float* __restrict__ ws1, const float* __restrict__ wn1,
    uint* __restrict__ w1t) {
  int idx = blockIdx.x * 256 + threadIdx.x;   // 128 cols * 128 uints
  if (idx >= 128 * 128) return;
  int col = idx >> 7, ku = idx & 127;
  int k = ku * 2;
  const float* w = (k < 128) ? ws1 : wn1;
  int kk = (k < 128) ? k : (k - 128);
  w1t[idx] = bf16_2(w[(size_t)kk * 128 + col], w[(size_t)(kk + 1) * 128 + col]);
}

// w2t[col][k] = bf16([ws2|wn2][k][col]), cols 0..15 = ws2, 16..31 = wn2, K=128.
__global__ __launch_bounds__(256) void prep_w2_kernel(
    const float* __restrict__ ws2, const float* __restrict__ wn2,
    uint* __restrict__ w2t) {
  int idx = blockIdx.x * 256 + threadIdx.x;   // 32 cols * 64 uints
  if (idx >= 32 * 64) return;
  int col = idx >> 6, ku = idx & 63;
  int k = ku * 2;
  const float* w = (col < 16) ? ws2 : wn2;
  int c = col & 15;
  w2t[idx] = bf16_2(w[(size_t)k * 16 + c], w[(size_t)(k + 1) * 16 + c]);
}

// ---------------------------------------------------------------------------
// Pass A: per-block bucket histogram, LDS atomics only, coalesced output.
// ---------------------------------------------------------------------------
__global__ __launch_bounds__(1024) void histA_kernel(
    const int* __restrict__ dst, int* __restrict__ hist2) {
  __shared__ int lh[NBUCK];
  int tid = threadIdx.x;
  int b = blockIdx.x;
  for (int i = tid; i < NBUCK; i += 1024) lh[i] = 0;
  __syncthreads();
  int e0 = b * CHUNK, e1 = min(e0 + CHUNK, NE);
  for (int e = e0 + tid; e < e1; e += 1024) {
    atomicAdd(&lh[dst[e] >> 6], 1);
  }
  __syncthreads();
  for (int i = tid; i < NBUCK; i += 1024)
    hist2[(size_t)b * NBUCK + i] = lh[i];
}

// ---------------------------------------------------------------------------
// Transpose hist2[NBLK][NBUCK] -> hist[NBUCK][NBLK].
// ---------------------------------------------------------------------------
__global__ __launch_bounds__(1024) void transpose_kernel(
    const int* __restrict__ hist2, int* __restrict__ hist) {
  __shared__ int t[32][33];
  int tx = threadIdx.x & 31, ty = threadIdx.x >> 5;
  int i = blockIdx.x * 32 + tx;
  int b = blockIdx.y * 32 + ty;
  if (i < NBUCK) t[ty][tx] = hist2[(size_t)b * NBUCK + i];
  __syncthreads();
  int i2 = blockIdx.x * 32 + ty;
  int b2 = blockIdx.y * 32 + tx;
  if (i2 < NBUCK) hist[(size_t)i2 * NBLK + b2] = t[tx][ty];
}

// ---------------------------------------------------------------------------
// Multi-block exclusive scan over hist[NH] (in-place), 3 kernels.
// ---------------------------------------------------------------------------
__global__ __launch_bounds__(1024) void scan_sums_kernel(
    const int* __restrict__ hist, int* __restrict__ sums) {
  __shared__ int sdata[1024];
  int i = blockIdx.x * 1024 + threadIdx.x;
  sdata[threadIdx.x] = (i < NH) ? hist[i] : 0;
  __syncthreads();
#pragma unroll
  for (int s = 512; s > 0; s >>= 1) {
    if (threadIdx.x < s) sdata[threadIdx.x] += sdata[threadIdx.x + s];
    __syncthreads();
  }
  if (threadIdx.x == 0) sums[blockIdx.x] = sdata[0];
}

__global__ __launch_bounds__(512) void scan_tops_kernel(int* __restrict__ sums) {
  __shared__ int buf[2][512];
  int tid = threadIdx.x;
  int v = (tid < NSB) ? sums[tid] : 0;
  buf[0][tid] = v;
  __syncthreads();
  int pp = 0;
#pragma unroll
  for (int d = 1; d < 512; d <<= 1) {
    buf[pp ^ 1][tid] = buf[pp][tid] + ((tid >= d) ? buf[pp][tid - d] : 0);
    pp ^= 1;
    __syncthreads();
  }
  if (tid < NSB) sums[tid] = buf[pp][tid] - v;  // exclusive
}

__global__ __launch_bounds__(1024) void scan_apply_kernel(
    int* __restrict__ hist, const int* __restrict__ sums) {
  __shared__ int buf[2][1024];
  int tid = threadIdx.x;
  int i = blockIdx.x * 1024 + tid;
  int v = (i < NH) ? hist[i] : 0;
  buf[0][tid] = v;
  __syncthreads();
  int pp = 0;
#pragma unroll
  for (int d = 1; d < 1024; d <<= 1) {
    buf[pp ^ 1][tid] = buf[pp][tid] + ((tid >= d) ? buf[pp][tid - d] : 0);
    pp ^= 1;
    __syncthreads();
  }
  if (i < NH) hist[i] = sums[blockIdx.x] + buf[pp][tid] - v;  // exclusive
}

// ---------------------------------------------------------------------------
// Pass C: contention-free scatter via scanned per-(bucket,block) cursors.
// ---------------------------------------------------------------------------
__global__ __launch_bounds__(1024) void scatter3_kernel(
    const int* __restrict__ src, const int* __restrict__ dst,
    const int* __restrict__ scanned, unsigned int* __restrict__ ebuf) {
  __shared__ int cur[NBUCK];
  int tid = threadIdx.x;
  int b = blockIdx.x;
  for (int i = tid; i < NBUCK; i += 1024) cur[i] = scanned[i * NBLK + b];
  __syncthreads();
  int e0 = b * CHUNK, e1 = min(e0 + CHUNK, NE);
  for (int e = e0 + tid; e < e1; e += 1024) {
    int d = dst[e];
    int p = atomicAdd(&cur[d >> 6], 1);
    ebuf[p] = ((unsigned int)(d & 63) << 17) | (unsigned int)src[e];
  }
}

// ---------------------------------------------------------------------------
// Per-bucket counting sort, two-pass (computes deg + off, no global atomics).
// ---------------------------------------------------------------------------
__global__ __launch_bounds__(256) void bucket_sort_kernel(
    const unsigned int* __restrict__ ebuf, const int* __restrict__ scanned,
    int* __restrict__ deg, int* __restrict__ off, int* __restrict__ perm) {
  __shared__ int cnt[BSZ];
  __shared__ int loc_off[BSZ];
  int tid = threadIdx.x;
  int b = blockIdx.x;
  int e0 = scanned[b * NBLK];
  int e1 = (b + 1 < NBUCK) ? scanned[(b + 1) * NBLK] : NE;

  if (tid < BSZ) cnt[tid] = 0;
  __syncthreads();
  for (int e = e0 + tid; e < e1; e += 256)
    atomicAdd(&cnt[ebuf[e] >> 17], 1);
  __syncthreads();

  if (tid < BSZ) {   // threads 0..63 = one wave
    int v = cnt[tid];
    int incl = v;
#pragma unroll
    for (int d = 1; d < 64; d <<= 1) {
      int t = __shfl_up(incl, d);
      if (tid >= d) incl += t;
    }
    int excl = incl - v;
    loc_off[tid] = e0 + excl;
    int node = b * BSZ + tid;
    if (node < NN) { off[node] = e0 + excl; deg[node] = v; }
    cnt[tid] = 0;
  }
  __syncthreads();

  for (int e = e0 + tid; e < e1; e += 256) {
    unsigned int pk = ebuf[e];
    int dl = pk >> 17;
    int p = loc_off[dl] + atomicAdd(&cnt[dl], 1);
    perm[p] = (int)(pk & 0x1FFFF);
  }
}

// ---------------------------------------------------------------------------
// Layer-1 mean aggregation, XCD-sliced: block (s, bucket) gathers only
// slice s (32B of each neighbor row) from the L2-resident 3.2MB slice table.
// slice = blockIdx&7 -> consecutive blocks hit different XCDs (round-robin).
// 16 edge slots x 4 lanes (uint2 = 4 feats each); dot2 accumulate; output
// slice-major m1s (matches gemm1's A addressing).
// ---------------------------------------------------------------------------
__global__ __launch_bounds__(256) void mean1_kernel(
    const uint* __restrict__ xs, const int* __restrict__ off,
    const int* __restrict__ deg, const int* __restrict__ perm,
    uint* __restrict__ m1s) {
  int s = blockIdx.x & 7;
  int bucket = blockIdx.x >> 3;
  int wv = threadIdx.x >> 6;
  int lane = threadIdx.x & 63;
  int slot = lane >> 2;   // 16 edge slots
  int q = lane & 3;       // uint2 index within the 8-uint slice row
  const uint* table = xs + (size_t)s * NN * 8;
  uint* outp = m1s + (size_t)s * NN * 8;

  int n0 = bucket * BSZ + wv * 16;
  for (int n = 0; n < 16; n++) {
    int node = n0 + n;
    if (node >= NN) break;
    int o = off[node], dg = deg[node];
    float A0 = 0.f, A1 = 0.f, A2 = 0.f, A3 = 0.f;
    for (int j = slot; j < dg; j += 16) {
      int sr = perm[o + j];
      uint2 v = *(const uint2*)(table + (size_t)sr * 8 + q * 2);
      dot2acc2(A0, A1, v.x);
      dot2acc2(A2, A3, v.y);
    }
#pragma unroll
    for (int d = 4; d <= 32; d <<= 1) {
      A0 += __shfl_xor(A0, d); A1 += __shfl_xor(A1, d);
      A2 += __shfl_xor(A2, d); A3 += __shfl_xor(A3, d);
    }
    if (slot == 0) {
      float rd = 1.0f / fmaxf((float)dg, 1.0f);
      uint2 o2;
      o2.x = bf16_2(A0 * rd, A1 * rd);
      o2.y = bf16_2(A2 * rd, A3 * rd);
      *(uint2*)(outp + (size_t)node * 8 + q * 2) = o2;
    }
  }
}

// ---------------------------------------------------------------------------
// GEMM1 (MFMA bf16, LDS-staged B): h = relu([x | mean1] @ w1t^T + b1).
// A operands read SLICE-MAJOR (xs / m1s): uint u of a row lives at
// slice u>>3, pos u&7. 32B row stride also improves A-load line density.
// ---------------------------------------------------------------------------
__global__ __launch_bounds__(256) void gemm1_mfma_kernel(
    const uint* __restrict__ xs, const uint* __restrict__ m1s,
    const uint* __restrict__ w1t, const float* __restrict__ b1,
    ushort_t* __restrict__ hout) {
  __shared__ uint lds_w[128 * 128];   // 64 KB
  int tid = threadIdx.x;

#pragma unroll
  for (int i = 0; i < 16; i++) {
    int g = tid + i * 256;
    int row = g >> 5, c = g & 31;
    uint4 v = ((const uint4*)w1t)[g];
    int cs = c ^ (row & 7);
    *(uint4*)&lds_w[row * 128 + cs * 4] = v;
  }
  __syncthreads();

  int wv = tid >> 6;
  int lane = tid & 63;
  int lr = lane & 15, lk = lane >> 4;
  int r0 = blockIdx.x * 256 + wv * 64;
  if (r0 >= NN) return;   // after the only barrier

  f32x4 acc[4][8];
#pragma unroll
  for (int i = 0; i < 4; i++)
#pragma unroll
    for (int j = 0; j < 8; j++) acc[i][j] = (f32x4){0.f, 0.f, 0.f, 0.f};

#pragma unroll
  for (int ks = 0; ks < 8; ks++) {
    const uint* T = (ks < 4) ? xs : m1s;
    int u = (ks & 3) * 16 + lk * 4;             // uint index within 64-uint row
    const uint* base = T + (size_t)(u >> 3) * NN * 8 + (u & 7);
    uint4 a[4];
#pragma unroll
    for (int rt = 0; rt < 4; rt++) {
      int row = r0 + rt * 16 + lr;
      if (row >= NN) row = NN - 1;
      a[rt] = *(const uint4*)(base + (size_t)row * 8);
    }
    int cbase = ks * 4 + lk;
#pragma unroll
    for (int ct = 0; ct < 8; ct++) {
      int brow = ct * 16 + lr;
      int cs = cbase ^ (lr & 7);
      uint4 bu = *(const uint4*)&lds_w[brow * 128 + cs * 4];
#pragma unroll
      for (int rt = 0; rt < 4; rt++)
        acc[rt][ct] = mfma_bf16(a[rt], bu, acc[rt][ct]);
    }
  }

  float bias[8];
#pragma unroll
  for (int ct = 0; ct < 8; ct++) bias[ct] = b1[ct * 16 + lr];

#pragma unroll
  for (int rt = 0; rt < 4; rt++) {
#pragma unroll
    for (int r = 0; r < 4; r++) {
      int row = r0 + rt * 16 + lk * 4 + r;
      if (row < NN) {
#pragma unroll
        for (int ct = 0; ct < 8; ct++) {
          int col = ct * 16 + lr;
          float v = fmaxf(acc[rt][ct][r] + bias[ct], 0.0f);
          hout[(size_t)row * 128 + col] = (ushort_t)bf16_1(v);
        }
      }
    }
  }
}

// ---------------------------------------------------------------------------
// GEMM2 (MFMA bf16): [oself | h2] = h @ w2t^T. K=128, N=32, fp32 out.
// ---------------------------------------------------------------------------
__global__ __launch_bounds__(256) void gemm2_mfma_kernel(
    const uint* __restrict__ h, const uint* __restrict__ w2t,
    float* __restrict__ oself, float* __restrict__ h2) {
  int wid = (blockIdx.x * 256 + threadIdx.x) >> 6;
  int lane = threadIdx.x & 63;
  int r0 = wid * 32;
  if (r0 >= NN) return;
  int lr = lane & 15, lk = lane >> 4;

  f32x4 acc[2][2];
#pragma unroll
  for (int i = 0; i < 2; i++)
#pragma unroll
    for (int j = 0; j < 2; j++) acc[i][j] = (f32x4){0.f, 0.f, 0.f, 0.f};

#pragma unroll
  for (int ks = 0; ks < 4; ks++) {
    int ku = ks * 16;
    uint4 a0 = *(const uint4*)(h + (size_t)(r0 + lr) * 64 + ku + lk * 4);
    uint4 a1 = *(const uint4*)(h + (size_t)(r0 + 16 + lr) * 64 + ku + lk * 4);
#pragma unroll
    for (int ct = 0; ct < 2; ct++) {
      uint4 bu = *(const uint4*)(w2t + (size_t)(ct * 16 + lr) * 64 + ku + lk * 4);
      acc[0][ct] = mfma_bf16(a0, bu, acc[0][ct]);
      acc[1][ct] = mfma_bf16(a1, bu, acc[1][ct]);
    }
  }

#pragma unroll
  for (int rt = 0; rt < 2; rt++) {
#pragma unroll
    for (int r = 0; r < 4; r++) {
      int row = r0 + rt * 16 + lk * 4 + r;
      oself[(size_t)row * 16 + lr] = acc[rt][0][r];
      h2[(size_t)row * 16 + lr]    = acc[rt][1][r];
    }
  }
}

// ---------------------------------------------------------------------------
// Layer-2 mean aggregation: one wave per node, float4/lane, 4 lanes/edge,
// 16 edges in parallel; shfl_xor tree reduce (4..32).
// ---------------------------------------------------------------------------
__global__ __launch_bounds__(256) void mean2_kernel(
    const float* __restrict__ h2, const int* __restrict__ off,
    const int* __restrict__ deg, const int* __restrict__ perm,
    float* __restrict__ mean2) {
  int node = blockIdx.x * 4 + (threadIdx.x >> 6);
  int lane = threadIdx.x & 63;
  if (node >= NN) return;
  int o = off[node], dg = deg[node];
  int sub = lane >> 2;   // 16 edge slots
  int q = lane & 3;      // float4 index within the 16-float row
  float ax = 0.f, ay = 0.f, az = 0.f, aw = 0.f;
  for (int j = sub; j < dg; j += 16) {
    int s = perm[o + j];
    float4 v = *(const float4*)(h2 + (size_t)s * 16 + q * 4);
    ax += v.x; ay += v.y; az += v.z; aw += v.w;
  }
#pragma unroll
  for (int d = 4; d <= 32; d <<= 1) {
    ax += __shfl_xor(ax, d); ay += __shfl_xor(ay, d);
    az += __shfl_xor(az, d); aw += __shfl_xor(aw, d);
  }
  if (sub == 0) {
    float rd = 1.0f / fmaxf((float)dg, 1.0f);
    float4 r; r.x = ax * rd; r.y = ay * rd; r.z = az * rd; r.w = aw * rd;
    *(float4*)(mean2 + (size_t)node * 16 + q * 4) = r;
  }
}

// ---------------------------------------------------------------------------
// Final: logits = oself + b2 + mean2; out = log_softmax(logits).
// ---------------------------------------------------------------------------
__global__ __launch_bounds__(256) void final_kernel(
    const float* __restrict__ oself, const float* __restrict__ mean2,
    const float* __restrict__ b2, float* __restrict__ out) {
  int i = blockIdx.x * 256 + threadIdx.x;
  if (i >= NN) return;
  float l[16];
  const float4* po = (const float4*)(oself + (size_t)i * 16);
  const float4* pa = (const float4*)(mean2 + (size_t)i * 16);
#pragma unroll
  for (int q = 0; q < 4; q++) {
    float4 o = po[q], a = pa[q];
    l[q * 4 + 0] = o.x + b2[q * 4 + 0] + a.x;
    l[q * 4 + 1] = o.y + b2[q * 4 + 1] + a.y;
    l[q * 4 + 2] = o.z + b2[q * 4 + 2] + a.z;
    l[q * 4 + 3] = o.w + b2[q * 4 + 3] + a.w;
  }
  float m = l[0];
#pragma unroll
  for (int c = 1; c < 16; c++) m = fmaxf(m, l[c]);
  float s = 0.0f;
#pragma unroll
  for (int c = 0; c < 16; c++) s += expf(l[c] - m);
  float ls = logf(s);
  float4* po2 = (float4*)(out + (size_t)i * 16);
#pragma unroll
  for (int q = 0; q < 4; q++) {
    float4 v;
    v.x = l[q * 4 + 0] - m - ls;
    v.y = l[q * 4 + 1] - m - ls;
    v.z = l[q * 4 + 2] - m - ls;
    v.w = l[q * 4 + 3] - m - ls;
    po2[q] = v;
  }
}

// ---------------------------------------------------------------------------
extern "C" void kernel_launch(void* const* d_in, const int* in_sizes, int n_in,
                              void* d_out, int out_size, void* d_ws, size_t ws_size,
                              hipStream_t stream) {
  const float* x   = (const float*)d_in[0];
  const int*   src = (const int*)d_in[1];
  const int*   dst = (const int*)d_in[2];
  const float* ws1 = (const float*)d_in[3];
  const float* wn1 = (const float*)d_in[4];
  const float* b1  = (const float*)d_in[5];
  const float* ws2 = (const float*)d_in[6];
  const float* wn2 = (const float*)d_in[7];
  const float* b2  = (const float*)d_in[8];
  float* out = (float*)d_out;

  // workspace layout
  char* p = (char*)d_ws;
  int* deg   = (int*)p;  p += (size_t)NN * 4;
  int* off   = (int*)p;  p += (size_t)NN * 4;
  int* hist  = (int*)p;  p += (size_t)NH * 4;            // bucket-major, scanned in place
  int* hist2 = (int*)p;  p += (size_t)NH * 4;            // block-major
  int* sums  = (int*)p;  p += (size_t)((NSB + 31) & ~31) * 4;
  unsigned int* ebuf = (unsigned int*)p; p += (size_t)NE * 4;
  int* perm = (int*)p;  p += (size_t)NE * 4;
  uint* xs   = (uint*)p; p += (size_t)NN * 64 * 4;       // bf16 x, slice-major
  uint* m1s  = (uint*)p; p += (size_t)NN * 64 * 4;       // bf16 mean1, slice-major
  uint* hbuf = (uint*)p; p += (size_t)NN * 64 * 4;       // bf16 h, row-major
  uint* w1t  = (uint*)p; p += (size_t)128 * 128 * 4;     // bf16 [ws1;wn1]^T
  uint* w2t  = (uint*)p; p += (size_t)32 * 64 * 4;       // bf16 [ws2|wn2]^T
  float* h2    = (float*)p; p += (size_t)NN * 16 * 4;
  float* osf   = (float*)p; p += (size_t)NN * 16 * 4;
  float* mean2 = (float*)p; p += (size_t)NN * 16 * 4;

  tobf16_kernel<<<(NN * 16 + 255) / 256, 256, 0, stream>>>(x, xs);
  prep_w1_kernel<<<(128 * 128 + 255) / 256, 256, 0, stream>>>(ws1, wn1, w1t);
  prep_w2_kernel<<<(32 * 64 + 255) / 256, 256, 0, stream>>>(ws2, wn2, w2t);

  histA_kernel<<<NBLK, 1024, 0, stream>>>(dst, hist2);
  transpose_kernel<<<dim3((NBUCK + 31) / 32, NBLK / 32), 1024, 0, stream>>>(
      hist2, hist);
  scan_sums_kernel<<<NSB, 1024, 0, stream>>>(hist, sums);
  scan_tops_kernel<<<1, 512, 0, stream>>>(sums);
  scan_apply_kernel<<<NSB, 1024, 0, stream>>>(hist, sums);
  scatter3_kernel<<<NBLK, 1024, 0, stream>>>(src, dst, hist, ebuf);
  bucket_sort_kernel<<<NBUCK, 256, 0, stream>>>(ebuf, hist, deg, off, perm);

  mean1_kernel<<<8 * NBUCK, 256, 0, stream>>>(xs, off, deg, perm, m1s);

  gemm1_mfma_kernel<<<(NN + 255) / 256, 256, 0, stream>>>(
      xs, m1s, w1t, b1, (ushort_t*)hbuf);
  gemm2_mfma_kernel<<<(NN + 127) / 128, 256, 0, stream>>>(hbuf, w2t, osf, h2);

  mean2_kernel<<<(NN + 3) / 4, 256, 0, stream>>>(h2, off, deg, perm, mean2);
  final_kernel<<<(NN + 255) / 256, 256, 0, stream>>>(osf, mean2, b2, out);
}

// Round 14
// 184.245 us; speedup vs baseline: 1.7053x; 1.7053x over previous
//
#include <hip/hip_runtime.h>
#include <math.h>

#define NN 100000
#define NE 1600000
#define BSZ 64                          // dst nodes per bucket
#define NBUCK ((NN + BSZ - 1) / BSZ)    // 1563
#define NBLK 256                        // scatter blocks / hist columns
#define CHUNK ((NE + NBLK - 1) / NBLK)  // 6250 edges per block
#define NH (NBUCK * NBLK)               // 400128 hist entries
#define NSB ((NH + 1023) / 1024)        // 391 scan blocks

typedef unsigned int uint;
typedef unsigned short ushort_t;
typedef float f32x2 __attribute__((ext_vector_type(2)));
typedef float f32x4 __attribute__((ext_vector_type(4)));
typedef short s16x8 __attribute__((ext_vector_type(8)));

union U4S8 { uint4 u; s16x8 s; };

// bf16 helpers (RNE pack)
__device__ inline uint bf16_1(float f) {
  uint u = __float_as_uint(f);
  return (u + 0x7FFFu + ((u >> 16) & 1u)) >> 16;
}
__device__ inline uint bf16_2(float lo, float hi) {
  return bf16_1(lo) | (bf16_1(hi) << 16);
}

__device__ inline f32x4 mfma_bf16(uint4 a, uint4 b, f32x4 c) {
  U4S8 ua, ub; ua.u = a; ub.u = b;
  return __builtin_amdgcn_mfma_f32_16x16x32_bf16(ua.s, ub.s, c, 0, 0, 0);
}

// ---------------------------------------------------------------------------
// x (fp32 [NN][128]) -> xh (bf16, [NN][64] uints) AND xq (fp8 e4m3,
// [NN][32] uints). xh feeds gemm1's self path; xq is the 12.8 MB gather
// table for mean1 (halves L2-miss bytes vs bf16).
// ---------------------------------------------------------------------------
__global__ __launch_bounds__(256) void tobf16_kernel(
    const float* __restrict__ x, uint* __restrict__ xh,
    uint* __restrict__ xq) {
  int i = blockIdx.x * 256 + threadIdx.x;
  if (i >= NN * 16) return;
  const float4* p = (const float4*)x + (size_t)i * 2;
  float4 a = p[0], b = p[1];
  uint4 o;
  o.x = bf16_2(a.x, a.y);
  o.y = bf16_2(a.z, a.w);
  o.z = bf16_2(b.x, b.y);
  o.w = bf16_2(b.z, b.w);
  ((uint4*)xh)[i] = o;
  // fp8 pack: 8 floats -> 2 uints
  int q0 = __builtin_amdgcn_cvt_pk_fp8_f32(a.x, a.y, 0, false);
  q0 = __builtin_amdgcn_cvt_pk_fp8_f32(a.z, a.w, q0, true);
  int q1 = __builtin_amdgcn_cvt_pk_fp8_f32(b.x, b.y, 0, false);
  q1 = __builtin_amdgcn_cvt_pk_fp8_f32(b.z, b.w, q1, true);
  uint2 oq; oq.x = (uint)q0; oq.y = (uint)q1;
  int r = i >> 4;
  int u = (i & 15) * 2;    // uint index 0..30 within the 32-uint fp8 row
  *(uint2*)(xq + (size_t)r * 32 + u) = oq;
}

// ---------------------------------------------------------------------------
// Weight prep: w1t[col][k] = bf16([ws1;wn1][k][col]), K=256 -> 128 uints/row.
// ---------------------------------------------------------------------------
__global__ __launch_bounds__(256) void prep_w1_kernel(
    const float* __restrict__ ws1, const float* __restrict__ wn1,
    uint* __restrict__ w1t) {
  int idx = blockIdx.x * 256 + threadIdx.x;   // 128 cols * 128 uints
  if (idx >= 128 * 128) return;
  int col = idx >> 7, ku = idx & 127;
  int k = ku * 2;
  const float* w = (k < 128) ? ws1 : wn1;
  int kk = (k < 128) ? k : (k - 128);
  w1t[idx] = bf16_2(w[(size_t)kk * 128 + col], w[(size_t)(kk + 1) * 128 + col]);
}

// w2t[col][k] = bf16([ws2|wn2][k][col]), cols 0..15 = ws2, 16..31 = wn2, K=128.
__global__ __launch_bounds__(256) void prep_w2_kernel(
    const float* __restrict__ ws2, const float* __restrict__ wn2,
    uint* __restrict__ w2t) {
  int idx = blockIdx.x * 256 + threadIdx.x;   // 32 cols * 64 uints
  if (idx >= 32 * 64) return;
  int col = idx >> 6, ku = idx & 63;
  int k = ku * 2;
  const float* w = (col < 16) ? ws2 : wn2;
  int c = col & 15;
  w2t[idx] = bf16_2(w[(size_t)k * 16 + c], w[(size_t)(k + 1) * 16 + c]);
}

// ---------------------------------------------------------------------------
// Pass A: per-block bucket histogram, LDS atomics only, coalesced output.
// ---------------------------------------------------------------------------
__global__ __launch_bounds__(1024) void histA_kernel(
    const int* __restrict__ dst, int* __restrict__ hist2) {
  __shared__ int lh[NBUCK];
  int tid = threadIdx.x;
  int b = blockIdx.x;
  for (int i = tid; i < NBUCK; i += 1024) lh[i] = 0;
  __syncthreads();
  int e0 = b * CHUNK, e1 = min(e0 + CHUNK, NE);
  for (int e = e0 + tid; e < e1; e += 1024) {
    atomicAdd(&lh[dst[e] >> 6], 1);
  }
  __syncthreads();
  for (int i = tid; i < NBUCK; i += 1024)
    hist2[(size_t)b * NBUCK + i] = lh[i];
}

// ---------------------------------------------------------------------------
// Transpose hist2[NBLK][NBUCK] -> hist[NBUCK][NBLK].
// ---------------------------------------------------------------------------
__global__ __launch_bounds__(1024) void transpose_kernel(
    const int* __restrict__ hist2, int* __restrict__ hist) {
  __shared__ int t[32][33];
  int tx = threadIdx.x & 31, ty = threadIdx.x >> 5;
  int i = blockIdx.x * 32 + tx;
  int b = blockIdx.y * 32 + ty;
  if (i < NBUCK) t[ty][tx] = hist2[(size_t)b * NBUCK + i];
  __syncthreads();
  int i2 = blockIdx.x * 32 + ty;
  int b2 = blockIdx.y * 32 + tx;
  if (i2 < NBUCK) hist[(size_t)i2 * NBLK + b2] = t[tx][ty];
}

// ---------------------------------------------------------------------------
// Multi-block exclusive scan over hist[NH] (in-place), 3 kernels.
// ---------------------------------------------------------------------------
__global__ __launch_bounds__(1024) void scan_sums_kernel(
    const int* __restrict__ hist, int* __restrict__ sums) {
  __shared__ int sdata[1024];
  int i = blockIdx.x * 1024 + threadIdx.x;
  sdata[threadIdx.x] = (i < NH) ? hist[i] : 0;
  __syncthreads();
#pragma unroll
  for (int s = 512; s > 0; s >>= 1) {
    if (threadIdx.x < s) sdata[threadIdx.x] += sdata[threadIdx.x + s];
    __syncthreads();
  }
  if (threadIdx.x == 0) sums[blockIdx.x] = sdata[0];
}

__global__ __launch_bounds__(512) void scan_tops_kernel(int* __restrict__ sums) {
  __shared__ int buf[2][512];
  int tid = threadIdx.x;
  int v = (tid < NSB) ? sums[tid] : 0;
  buf[0][tid] = v;
  __syncthreads();
  int pp = 0;
#pragma unroll
  for (int d = 1; d < 512; d <<= 1) {
    buf[pp ^ 1][tid] = buf[pp][tid] + ((tid >= d) ? buf[pp][tid - d] : 0);
    pp ^= 1;
    __syncthreads();
  }
  if (tid < NSB) sums[tid] = buf[pp][tid] - v;  // exclusive
}

__global__ __launch_bounds__(1024) void scan_apply_kernel(
    int* __restrict__ hist, const int* __restrict__ sums) {
  __shared__ int buf[2][1024];
  int tid = threadIdx.x;
  int i = blockIdx.x * 1024 + tid;
  int v = (i < NH) ? hist[i] : 0;
  buf[0][tid] = v;
  __syncthreads();
  int pp = 0;
#pragma unroll
  for (int d = 1; d < 1024; d <<= 1) {
    buf[pp ^ 1][tid] = buf[pp][tid] + ((tid >= d) ? buf[pp][tid - d] : 0);
    pp ^= 1;
    __syncthreads();
  }
  if (i < NH) hist[i] = sums[blockIdx.x] + buf[pp][tid] - v;  // exclusive
}

// ---------------------------------------------------------------------------
// Pass C: contention-free scatter via scanned per-(bucket,block) cursors.
// ---------------------------------------------------------------------------
__global__ __launch_bounds__(1024) void scatter3_kernel(
    const int* __restrict__ src, const int* __restrict__ dst,
    const int* __restrict__ scanned, unsigned int* __restrict__ ebuf) {
  __shared__ int cur[NBUCK];
  int tid = threadIdx.x;
  int b = blockIdx.x;
  for (int i = tid; i < NBUCK; i += 1024) cur[i] = scanned[i * NBLK + b];
  __syncthreads();
  int e0 = b * CHUNK, e1 = min(e0 + CHUNK, NE);
  for (int e = e0 + tid; e < e1; e += 1024) {
    int d = dst[e];
    int p = atomicAdd(&cur[d >> 6], 1);
    ebuf[p] = ((unsigned int)(d & 63) << 17) | (unsigned int)src[e];
  }
}

// ---------------------------------------------------------------------------
// Per-bucket counting sort, two-pass (computes deg + off, no global atomics).
// ---------------------------------------------------------------------------
__global__ __launch_bounds__(256) void bucket_sort_kernel(
    const unsigned int* __restrict__ ebuf, const int* __restrict__ scanned,
    int* __restrict__ deg, int* __restrict__ off, int* __restrict__ perm) {
  __shared__ int cnt[BSZ];
  __shared__ int loc_off[BSZ];
  int tid = threadIdx.x;
  int b = blockIdx.x;
  int e0 = scanned[b * NBLK];
  int e1 = (b + 1 < NBUCK) ? scanned[(b + 1) * NBLK] : NE;

  if (tid < BSZ) cnt[tid] = 0;
  __syncthreads();
  for (int e = e0 + tid; e < e1; e += 256)
    atomicAdd(&cnt[ebuf[e] >> 17], 1);
  __syncthreads();

  if (tid < BSZ) {   // threads 0..63 = one wave
    int v = cnt[tid];
    int incl = v;
#pragma unroll
    for (int d = 1; d < 64; d <<= 1) {
      int t = __shfl_up(incl, d);
      if (tid >= d) incl += t;
    }
    int excl = incl - v;
    loc_off[tid] = e0 + excl;
    int node = b * BSZ + tid;
    if (node < NN) { off[node] = e0 + excl; deg[node] = v; }
    cnt[tid] = 0;
  }
  __syncthreads();

  for (int e = e0 + tid; e < e1; e += 256) {
    unsigned int pk = ebuf[e];
    int dl = pk >> 17;
    int p = loc_off[dl] + atomicAdd(&cnt[dl], 1);
    perm[p] = (int)(pk & 0x1FFFF);
  }
}

// ---------------------------------------------------------------------------
// Layer-1 mean aggregation from fp8 rows (128B): one wave per node,
// uint4 (16 fp8) per lane, 8 lanes per row, 8 edges in parallel, unroll x2
// -> 16 gathers in flight. v_cvt_pk_f32_fp8 decode, fp32 accumulate,
// bf16 output (feeds gemm1 directly).
// ---------------------------------------------------------------------------
__global__ __launch_bounds__(256) void mean1_kernel(
    const uint* __restrict__ xq, const int* __restrict__ off,
    const int* __restrict__ deg, const int* __restrict__ perm,
    uint* __restrict__ m1h) {
  int node = blockIdx.x * 4 + (threadIdx.x >> 6);
  int lane = threadIdx.x & 63;
  if (node >= NN) return;
  int o = off[node], dg = deg[node];
  int slot = lane >> 3;   // 8 edge slots
  int q = lane & 7;       // uint4 index within the 32-uint fp8 row
  f32x2 A[8];
#pragma unroll
  for (int t = 0; t < 8; t++) A[t] = (f32x2){0.f, 0.f};
  int j = slot;
  for (; j + 8 < dg; j += 16) {   // 2 gathers in flight per lane
    int s0 = perm[o + j];
    int s1 = perm[o + j + 8];
    uint4 v0 = *(const uint4*)(xq + (size_t)s0 * 32 + q * 4);
    uint4 v1 = *(const uint4*)(xq + (size_t)s1 * 32 + q * 4);
    A[0] += __builtin_amdgcn_cvt_pk_f32_fp8(v0.x, 0);
    A[1] += __builtin_amdgcn_cvt_pk_f32_fp8(v0.x, 1);
    A[2] += __builtin_amdgcn_cvt_pk_f32_fp8(v0.y, 0);
    A[3] += __builtin_amdgcn_cvt_pk_f32_fp8(v0.y, 1);
    A[4] += __builtin_amdgcn_cvt_pk_f32_fp8(v0.z, 0);
    A[5] += __builtin_amdgcn_cvt_pk_f32_fp8(v0.z, 1);
    A[6] += __builtin_amdgcn_cvt_pk_f32_fp8(v0.w, 0);
    A[7] += __builtin_amdgcn_cvt_pk_f32_fp8(v0.w, 1);
    A[0] += __builtin_amdgcn_cvt_pk_f32_fp8(v1.x, 0);
    A[1] += __builtin_amdgcn_cvt_pk_f32_fp8(v1.x, 1);
    A[2] += __builtin_amdgcn_cvt_pk_f32_fp8(v1.y, 0);
    A[3] += __builtin_amdgcn_cvt_pk_f32_fp8(v1.y, 1);
    A[4] += __builtin_amdgcn_cvt_pk_f32_fp8(v1.z, 0);
    A[5] += __builtin_amdgcn_cvt_pk_f32_fp8(v1.z, 1);
    A[6] += __builtin_amdgcn_cvt_pk_f32_fp8(v1.w, 0);
    A[7] += __builtin_amdgcn_cvt_pk_f32_fp8(v1.w, 1);
  }
  if (j < dg) {
    int s0 = perm[o + j];
    uint4 v0 = *(const uint4*)(xq + (size_t)s0 * 32 + q * 4);
    A[0] += __builtin_amdgcn_cvt_pk_f32_fp8(v0.x, 0);
    A[1] += __builtin_amdgcn_cvt_pk_f32_fp8(v0.x, 1);
    A[2] += __builtin_amdgcn_cvt_pk_f32_fp8(v0.y, 0);
    A[3] += __builtin_amdgcn_cvt_pk_f32_fp8(v0.y, 1);
    A[4] += __builtin_amdgcn_cvt_pk_f32_fp8(v0.z, 0);
    A[5] += __builtin_amdgcn_cvt_pk_f32_fp8(v0.z, 1);
    A[6] += __builtin_amdgcn_cvt_pk_f32_fp8(v0.w, 0);
    A[7] += __builtin_amdgcn_cvt_pk_f32_fp8(v0.w, 1);
  }
  // reduce across the 8 edge slots (xor 8, 16, 32)
#pragma unroll
  for (int d = 8; d <= 32; d <<= 1) {
#pragma unroll
    for (int t = 0; t < 8; t++) {
      A[t].x += __shfl_xor(A[t].x, d);
      A[t].y += __shfl_xor(A[t].y, d);
    }
  }
  if (slot == 0) {
    float rd = 1.0f / fmaxf((float)dg, 1.0f);
    uint4 o0, o1;
    o0.x = bf16_2(A[0].x * rd, A[0].y * rd);
    o0.y = bf16_2(A[1].x * rd, A[1].y * rd);
    o0.z = bf16_2(A[2].x * rd, A[2].y * rd);
    o0.w = bf16_2(A[3].x * rd, A[3].y * rd);
    o1.x = bf16_2(A[4].x * rd, A[4].y * rd);
    o1.y = bf16_2(A[5].x * rd, A[5].y * rd);
    o1.z = bf16_2(A[6].x * rd, A[6].y * rd);
    o1.w = bf16_2(A[7].x * rd, A[7].y * rd);
    uint* pm = m1h + (size_t)node * 64 + q * 8;
    *(uint4*)pm = o0;
    *(uint4*)(pm + 4) = o1;
  }
}

// ---------------------------------------------------------------------------
// GEMM1 (MFMA bf16, LDS-staged B): h = relu([xh | m1h] @ w1t^T + b1).
// Block stages w1t (64 KB) into LDS once, XOR-swizzled; each wave computes
// 64 rows x 128 cols: per k-step 4 A-loads + 8 ds_read B + 32 MFMA.
// ---------------------------------------------------------------------------
__global__ __launch_bounds__(256) void gemm1_mfma_kernel(
    const uint* __restrict__ xh, const uint* __restrict__ m1h,
    const uint* __restrict__ w1t, const float* __restrict__ b1,
    ushort_t* __restrict__ hout) {
  __shared__ uint lds_w[128 * 128];   // 64 KB
  int tid = threadIdx.x;

#pragma unroll
  for (int i = 0; i < 16; i++) {
    int g = tid + i * 256;
    int row = g >> 5, c = g & 31;
    uint4 v = ((const uint4*)w1t)[g];
    int cs = c ^ (row & 7);
    *(uint4*)&lds_w[row * 128 + cs * 4] = v;
  }
  __syncthreads();

  int wv = tid >> 6;
  int lane = tid & 63;
  int lr = lane & 15, lk = lane >> 4;
  int r0 = blockIdx.x * 256 + wv * 64;
  if (r0 >= NN) return;   // after the only barrier

  f32x4 acc[4][8];
#pragma unroll
  for (int i = 0; i < 4; i++)
#pragma unroll
    for (int j = 0; j < 8; j++) acc[i][j] = (f32x4){0.f, 0.f, 0.f, 0.f};

#pragma unroll
  for (int ks = 0; ks < 8; ks++) {
    const uint* A = (ks < 4) ? xh : m1h;
    int ku = (ks & 3) * 16 + lk * 4;
    uint4 a[4];
#pragma unroll
    for (int rt = 0; rt < 4; rt++) {
      int row = r0 + rt * 16 + lr;
      if (row >= NN) row = NN - 1;
      a[rt] = *(const uint4*)(A + (size_t)row * 64 + ku);
    }
    int cbase = ks * 4 + lk;
#pragma unroll
    for (int ct = 0; ct < 8; ct++) {
      int brow = ct * 16 + lr;
      int cs = cbase ^ (lr & 7);
      uint4 bu = *(const uint4*)&lds_w[brow * 128 + cs * 4];
#pragma unroll
      for (int rt = 0; rt < 4; rt++)
        acc[rt][ct] = mfma_bf16(a[rt], bu, acc[rt][ct]);
    }
  }

  float bias[8];
#pragma unroll
  for (int ct = 0; ct < 8; ct++) bias[ct] = b1[ct * 16 + lr];

#pragma unroll
  for (int rt = 0; rt < 4; rt++) {
#pragma unroll
    for (int r = 0; r < 4; r++) {
      int row = r0 + rt * 16 + lk * 4 + r;
      if (row < NN) {
#pragma unroll
        for (int ct = 0; ct < 8; ct++) {
          int col = ct * 16 + lr;
          float v = fmaxf(acc[rt][ct][r] + bias[ct], 0.0f);
          hout[(size_t)row * 128 + col] = (ushort_t)bf16_1(v);
        }
      }
    }
  }
}

// ---------------------------------------------------------------------------
// GEMM2 (MFMA bf16): [oself | h2] = h @ w2t^T. K=128, N=32, fp32 out.
// ---------------------------------------------------------------------------
__global__ __launch_bounds__(256) void gemm2_mfma_kernel(
    const uint* __restrict__ h, const uint* __restrict__ w2t,
    float* __restrict__ oself, float* __restrict__ h2) {
  int wid = (blockIdx.x * 256 + threadIdx.x) >> 6;
  int lane = threadIdx.x & 63;
  int r0 = wid * 32;
  if (r0 >= NN) return;
  int lr = lane & 15, lk = lane >> 4;

  f32x4 acc[2][2];
#pragma unroll
  for (int i = 0; i < 2; i++)
#pragma unroll
    for (int j = 0; j < 2; j++) acc[i][j] = (f32x4){0.f, 0.f, 0.f, 0.f};

#pragma unroll
  for (int ks = 0; ks < 4; ks++) {
    int ku = ks * 16;
    uint4 a0 = *(const uint4*)(h + (size_t)(r0 + lr) * 64 + ku + lk * 4);
    uint4 a1 = *(const uint4*)(h + (size_t)(r0 + 16 + lr) * 64 + ku + lk * 4);
#pragma unroll
    for (int ct = 0; ct < 2; ct++) {
      uint4 bu = *(const uint4*)(w2t + (size_t)(ct * 16 + lr) * 64 + ku + lk * 4);
      acc[0][ct] = mfma_bf16(a0, bu, acc[0][ct]);
      acc[1][ct] = mfma_bf16(a1, bu, acc[1][ct]);
    }
  }

#pragma unroll
  for (int rt = 0; rt < 2; rt++) {
#pragma unroll
    for (int r = 0; r < 4; r++) {
      int row = r0 + rt * 16 + lk * 4 + r;
      oself[(size_t)row * 16 + lr] = acc[rt][0][r];
      h2[(size_t)row * 16 + lr]    = acc[rt][1][r];
    }
  }
}

// ---------------------------------------------------------------------------
// Layer-2 mean aggregation: one wave per node, float4/lane, 4 lanes/edge,
// 16 edges in parallel; shfl_xor tree reduce (4..32).
// ---------------------------------------------------------------------------
__global__ __launch_bounds__(256) void mean2_kernel(
    const float* __restrict__ h2, const int* __restrict__ off,
    const int* __restrict__ deg, const int* __restrict__ perm,
    float* __restrict__ mean2) {
  int node = blockIdx.x * 4 + (threadIdx.x >> 6);
  int lane = threadIdx.x & 63;
  if (node >= NN) return;
  int o = off[node], dg = deg[node];
  int sub = lane >> 2;   // 16 edge slots
  int q = lane & 3;      // float4 index within the 16-float row
  float ax = 0.f, ay = 0.f, az = 0.f, aw = 0.f;
  for (int j = sub; j < dg; j += 16) {
    int s = perm[o + j];
    float4 v = *(const float4*)(h2 + (size_t)s * 16 + q * 4);
    ax += v.x; ay += v.y; az += v.z; aw += v.w;
  }
#pragma unroll
  for (int d = 4; d <= 32; d <<= 1) {
    ax += __shfl_xor(ax, d); ay += __shfl_xor(ay, d);
    az += __shfl_xor(az, d); aw += __shfl_xor(aw, d);
  }
  if (sub == 0) {
    float rd = 1.0f / fmaxf((float)dg, 1.0f);
    float4 r; r.x = ax * rd; r.y = ay * rd; r.z = az * rd; r.w = aw * rd;
    *(float4*)(mean2 + (size_t)node * 16 + q * 4) = r;
  }
}

// ---------------------------------------------------------------------------
// Final: logits = oself + b2 + mean2; out = log_softmax(logits).
// ---------------------------------------------------------------------------
__global__ __launch_bounds__(256) void final_kernel(
    const float* __restrict__ oself, const float* __restrict__ mean2,
    const float* __restrict__ b2, float* __restrict__ out) {
  int i = blockIdx.x * 256 + threadIdx.x;
  if (i >= NN) return;
  float l[16];
  const float4* po = (const float4*)(oself + (size_t)i * 16);
  const float4* pa = (const float4*)(mean2 + (size_t)i * 16);
#pragma unroll
  for (int q = 0; q < 4; q++) {
    float4 o = po[q], a = pa[q];
    l[q * 4 + 0] = o.x + b2[q * 4 + 0] + a.x;
    l[q * 4 + 1] = o.y + b2[q * 4 + 1] + a.y;
    l[q * 4 + 2] = o.z + b2[q * 4 + 2] + a.z;
    l[q * 4 + 3] = o.w + b2[q * 4 + 3] + a.w;
  }
  float m = l[0];
#pragma unroll
  for (int c = 1; c < 16; c++) m = fmaxf(m, l[c]);
  float s = 0.0f;
#pragma unroll
  for (int c = 0; c < 16; c++) s += expf(l[c] - m);
  float ls = logf(s);
  float4* po2 = (float4*)(out + (size_t)i * 16);
#pragma unroll
  for (int q = 0; q < 4; q++) {
    float4 v;
    v.x = l[q * 4 + 0] - m - ls;
    v.y = l[q * 4 + 1] - m - ls;
    v.z = l[q * 4 + 2] - m - ls;
    v.w = l[q * 4 + 3] - m - ls;
    po2[q] = v;
  }
}

// ---------------------------------------------------------------------------
extern "C" void kernel_launch(void* const* d_in, const int* in_sizes, int n_in,
                              void* d_out, int out_size, void* d_ws, size_t ws_size,
                              hipStream_t stream) {
  const float* x   = (const float*)d_in[0];
  const int*   src = (const int*)d_in[1];
  const int*   dst = (const int*)d_in[2];
  const float* ws1 = (const float*)d_in[3];
  const float* wn1 = (const float*)d_in[4];
  const float* b1  = (const float*)d_in[5];
  const float* ws2 = (const float*)d_in[6];
  const float* wn2 = (const float*)d_in[7];
  const float* b2  = (const float*)d_in[8];
  float* out = (float*)d_out;

  // workspace layout (xq aliases hbuf: xq dead before gemm1 writes hbuf)
  char* p = (char*)d_ws;
  int* deg   = (int*)p;  p += (size_t)NN * 4;
  int* off   = (int*)p;  p += (size_t)NN * 4;
  int* hist  = (int*)p;  p += (size_t)NH * 4;            // bucket-major, scanned in place
  int* hist2 = (int*)p;  p += (size_t)NH * 4;            // block-major
  int* sums  = (int*)p;  p += (size_t)((NSB + 31) & ~31) * 4;
  unsigned int* ebuf = (unsigned int*)p; p += (size_t)NE * 4;
  int* perm = (int*)p;  p += (size_t)NE * 4;
  uint* xh   = (uint*)p; p += (size_t)NN * 64 * 4;       // bf16 x, row-major
  uint* m1h  = (uint*)p; p += (size_t)NN * 64 * 4;       // bf16 mean1, row-major
  uint* hbuf = (uint*)p; p += (size_t)NN * 64 * 4;       // bf16 h (gemm1 out)
  uint* xq   = hbuf;                                     // fp8 x (12.8 MB), dead before hbuf written
  uint* w1t  = (uint*)p; p += (size_t)128 * 128 * 4;     // bf16 [ws1;wn1]^T
  uint* w2t  = (uint*)p; p += (size_t)32 * 64 * 4;       // bf16 [ws2|wn2]^T
  float* h2    = (float*)p; p += (size_t)NN * 16 * 4;
  float* osf   = (float*)p; p += (size_t)NN * 16 * 4;
  float* mean2 = (float*)p; p += (size_t)NN * 16 * 4;

  tobf16_kernel<<<(NN * 16 + 255) / 256, 256, 0, stream>>>(x, xh, xq);
  prep_w1_kernel<<<(128 * 128 + 255) / 256, 256, 0, stream>>>(ws1, wn1, w1t);
  prep_w2_kernel<<<(32 * 64 + 255) / 256, 256, 0, stream>>>(ws2, wn2, w2t);

  histA_kernel<<<NBLK, 1024, 0, stream>>>(dst, hist2);
  transpose_kernel<<<dim3((NBUCK + 31) / 32, NBLK / 32), 1024, 0, stream>>>(
      hist2, hist);
  scan_sums_kernel<<<NSB, 1024, 0, stream>>>(hist, sums);
  scan_tops_kernel<<<1, 512, 0, stream>>>(sums);
  scan_apply_kernel<<<NSB, 1024, 0, stream>>>(hist, sums);
  scatter3_kernel<<<NBLK, 1024, 0, stream>>>(src, dst, hist, ebuf);
  bucket_sort_kernel<<<NBUCK, 256, 0, stream>>>(ebuf, hist, deg, off, perm);

  mean1_kernel<<<(NN + 3) / 4, 256, 0, stream>>>(xq, off, deg, perm, m1h);

  gemm1_mfma_kernel<<<(NN + 255) / 256, 256, 0, stream>>>(
      xh, m1h, w1t, b1, (ushort_t*)hbuf);
  gemm2_mfma_kernel<<<(NN + 127) / 128, 256, 0, stream>>>(hbuf, w2t, osf, h2);

  mean2_kernel<<<(NN + 3) / 4, 256, 0, stream>>>(h2, off, deg, perm, mean2);
  final_kernel<<<(NN + 255) / 256, 256, 0, stream>>>(osf, mean2, b2, out);
}